// Round 18
// baseline (139.024 us; speedup 1.0000x reference)
//
#include <hip/hip_runtime.h>

typedef float v2f __attribute__((ext_vector_type(2)));

constexpr int NX = 192, NY = 192, NZ = 192, NB = 2;
constexpr int ZPT  = 6;            // z outputs per thread
constexpr int TZ   = 32;           // lanes per z-line (NZ/ZPT); wave = 2 z-lines
constexpr int BY   = 6;            // y rows per block
constexpr int XSEG = 4;            // x outputs per block
constexpr int BLOCK_THREADS = TZ * BY;   // 192 = 3 waves
constexpr int PLANE = NY * NZ;
constexpr int NYT = NY / BY;       // 32
constexpr int NXB = NX / XSEG;     // 48
constexpr int NBLK = NYT * NXB * NB;     // 3072 blocks
constexpr int ROWS = BY + 2;             // 8 staged y-rows per tensor
constexpr int TILE_F = 2 * ROWS * NZ;    // 3072 floats = 12,288 B per buffer
// staging: 2 tensors x 8 rows x 48 float4 = 768 units = exactly 4 per thread

// full-wave DPP shifts, bound_ctrl=1 -> zero fill at lanes 0/63. The lane31/32
// seam (between the wave's two z-lines) is zeroed by the wm/we multiplies.
__device__ __forceinline__ float wshr1(float v) {   // lane n <- lane n-1
    return __int_as_float(__builtin_amdgcn_update_dpp(
        0, __float_as_int(v), 0x138, 0xf, 0xf, true));
}
__device__ __forceinline__ float wshl1(float v) {   // lane n <- lane n+1
    return __int_as_float(__builtin_amdgcn_update_dpp(
        0, __float_as_int(v), 0x130, 0xf, 0xf, true));
}

// Fold one staged x-plane. Own-z reads: 3 ds_read_b64 per row-tensor at 24B
// lane stride (64 lanes x 2 dwords = exactly 4 accesses/bank -> conflict-free,
// verified 0 conflicts in R17's variant). Edge taps z0-1 / z0+6 via DPP.
template<bool SAFE>
__device__ __forceinline__ void foldLDS(const float* __restrict__ buf,
    int ty, int tx, const float wy[3], float wx, float wm, float we,
    v2f W[5][3])
{
    v2f SA[5], SB[5], SC[5], SD[5];
    #pragma unroll
    for (int r = 0; r < 3; ++r) {
        const float* Lt = buf + (ty + r) * NZ + 6 * tx;   // label row slice
        const float* Lp = Lt + ROWS * NZ;                 // pred row slice
        const float2 t01 = *reinterpret_cast<const float2*>(Lt);
        const float2 t23 = *reinterpret_cast<const float2*>(Lt + 2);
        const float2 t45 = *reinterpret_cast<const float2*>(Lt + 4);
        const float2 p01 = *reinterpret_cast<const float2*>(Lp);
        const float2 p23 = *reinterpret_cast<const float2*>(Lp + 2);
        const float2 p45 = *reinterpret_cast<const float2*>(Lp + 4);
        // z0-1 = prev lane's last elem; z0+6 = next lane's first elem.
        // wm/we (in {0,1}) zero the volume z-boundaries AND the lane31/32 seam.
        const float tm = wshr1(t45.y) * wm, te = wshl1(t01.x) * we;
        const float pm = wshr1(p45.y) * wm, pe = wshl1(p01.x) * we;
        v2f TA{tm, t01.x}, TB{t01.y, t23.x}, TC{t23.y, t45.x}, TD{t45.y, te};
        v2f PA{pm, p01.x}, PB{p01.y, p23.x}, PC{p23.y, p45.x}, PD{p45.y, pe};
        if (!SAFE) {
            const float wr = wx * wy[r];        // w in {0,1} => exact masking
            TA *= wr; TB *= wr; TC *= wr; TD *= wr;
            PA *= wr; PB *= wr; PC *= wr; PD *= wr;
        }
        if (r == 0) {
            SA[0]=TA;     SB[0]=TB;     SC[0]=TC;     SD[0]=TD;
            SA[1]=PA;     SB[1]=PB;     SC[1]=PC;     SD[1]=PD;
            SA[2]=TA*TA;  SB[2]=TB*TB;  SC[2]=TC*TC;  SD[2]=TD*TD;
            SA[3]=PA*PA;  SB[3]=PB*PB;  SC[3]=PC*PC;  SD[3]=PD*PD;
            SA[4]=TA*PA;  SB[4]=TB*PB;  SC[4]=TC*PC;  SD[4]=TD*PD;
        } else {
            SA[0]+=TA;     SB[0]+=TB;     SC[0]+=TC;     SD[0]+=TD;
            SA[1]+=PA;     SB[1]+=PB;     SC[1]+=PC;     SD[1]+=PD;
            SA[2]+=TA*TA;  SB[2]+=TB*TB;  SC[2]+=TC*TC;  SD[2]+=TD*TD;
            SA[3]+=PA*PA;  SB[3]+=PB*PB;  SC[3]+=PC*PC;  SD[3]+=PD*PD;
            SA[4]+=TA*PA;  SB[4]+=TB*PB;  SC[4]+=TC*PC;  SD[4]+=TD*PD;
        }
    }
    // z-fold: taps s0..s7 -> 6 windows w_j = s_j + s_{j+1} + s_{j+2}
    #pragma unroll
    for (int q = 0; q < 5; ++q) {
        const float s0 = SA[q].x, s1 = SA[q].y, s2 = SB[q].x, s3 = SB[q].y;
        const float s4 = SC[q].x, s5 = SC[q].y, s6 = SD[q].x, s7 = SD[q].y;
        const float a = s1 + s2, b = s3 + s4, c = s5 + s6;
        W[q][0] = v2f{s0 + a, a + s3};
        W[q][1] = v2f{s2 + b, b + s5};
        W[q][2] = v2f{s4 + c, c + s7};
    }
}

// NCC for 6 z-outputs given full 27-voxel window sums
__device__ __forceinline__ float epilogue6(const v2f P[5][3], const v2f Wn[5][3])
{
    constexpr float inv_vol = 1.0f / 27.0f;
    float acc = 0.f;
    #pragma unroll
    for (int h = 0; h < 3; ++h) {
        const v2f st  = P[0][h] + Wn[0][h];
        const v2f sp  = P[1][h] + Wn[1][h];
        const v2f st2 = P[2][h] + Wn[2][h];
        const v2f sp2 = P[3][h] + Wn[3][h];
        const v2f stp = P[4][h] + Wn[4][h];
        const v2f tavg = st * inv_vol;
        const v2f pavg = sp * inv_vol;
        const v2f cross = stp - pavg * st;
        const v2f tvp   = st2 - tavg * st;
        const v2f pvp   = sp2 - pavg * sp;
        const v2f cc    = cross * cross;
        #pragma unroll
        for (int c = 0; c < 2; ++c) {
            const float tvar = fmaxf(tvp[c], 0.f);
            const float pvar = fmaxf(pvp[c], 0.f);
            acc += cc[c] * __builtin_amdgcn_rcpf(fmaf(tvar, pvar, 1e-5f));
        }
    }
    return acc;
}

// R8/R13's proven 6-plane double-buffered march, 4 staging units per thread.
template<bool SAFE>
__device__ __forceinline__ float march(
    const float* sb0, const float* sb1, const float* sb2, const float* sb3,
    int lo0, int lo1, int lo2, int lo3,
    float (*tile)[TILE_F],
    int ty, int tx, const float wy[3], float wm, float we, int xs0)
{
    v2f U[5][3], V[5][3], P[5][3];
    float acc = 0.f;
    float4 G0, G1, G2, G3;

#define XOFF(K) (SAFE ? (xs0 - 1 + (K)) * PLANE \
                      : min(max(xs0 - 1 + (K), 0), NX - 1) * PLANE)
#define WXK(K)  (SAFE ? 1.f : (((unsigned)(xs0 - 1 + (K)) < (unsigned)NX) ? 1.f : 0.f))
#define GLOAD(K) do { const int _xo = XOFF(K);                                  \
        G0 = *reinterpret_cast<const float4*>(sb0 + _xo);                       \
        G1 = *reinterpret_cast<const float4*>(sb1 + _xo);                       \
        G2 = *reinterpret_cast<const float4*>(sb2 + _xo);                       \
        G3 = *reinterpret_cast<const float4*>(sb3 + _xo); } while (0)
#define DSWR(K) do { float* _d = tile[(K) & 1];                                 \
        *reinterpret_cast<float4*>(_d + lo0) = G0;                              \
        *reinterpret_cast<float4*>(_d + lo1) = G1;                              \
        *reinterpret_cast<float4*>(_d + lo2) = G2;                              \
        *reinterpret_cast<float4*>(_d + lo3) = G3; } while (0)
#define FOLD(K, WDST) foldLDS<SAFE>(tile[(K) & 1], ty, tx, wy, WXK(K), wm, we, WDST)
#define PSET(A, B) do { _Pragma("unroll")                                       \
        for (int q = 0; q < 5; ++q) { _Pragma("unroll")                         \
            for (int h = 0; h < 3; ++h) P[q][h] = A[q][h] + B[q][h]; } } while (0)

    GLOAD(0); DSWR(0); __syncthreads();
    GLOAD(1); FOLD(0, U);             DSWR(1); __syncthreads();
    GLOAD(2); FOLD(1, V); PSET(U, V); DSWR(2); __syncthreads();
    GLOAD(3); FOLD(2, U); acc += epilogue6(P, U); PSET(V, U); DSWR(3); __syncthreads();
    GLOAD(4); FOLD(3, V); acc += epilogue6(P, V); PSET(U, V); DSWR(4); __syncthreads();
    GLOAD(5); FOLD(4, U); acc += epilogue6(P, U); PSET(V, U); DSWR(5); __syncthreads();
              FOLD(5, V); acc += epilogue6(P, V);

#undef XOFF
#undef WXK
#undef GLOAD
#undef DSWR
#undef FOLD
#undef PSET
    return acc;
}

__global__ __launch_bounds__(BLOCK_THREADS, 3)
void ncc_partial(const float* __restrict__ pred, const float* __restrict__ label,
                 float* __restrict__ partials)
{
    __shared__ alignas(16) float tile[2][TILE_F];    // 24,576 B

    const int tx  = threadIdx.x;                     // 0..31: z-line lane
    const int ty  = threadIdx.y;                     // 0..5:  y row
    const int tid = tx + ty * TZ;
    const int Y0  = blockIdx.x * BY;
    const int y   = Y0 + ty;
    const int xs0 = blockIdx.y * XSEG;
    const int b   = blockIdx.z;
    const int bbase = b * NX * PLANE;

    // staging: 768 float4 units = [tensor 2][row 8][z4 48]; exactly 4/thread
    const float* sbv[4]; int lov[4];
    #pragma unroll
    for (int k = 0; k < 4; ++k) {
        const int u   = tid + k * BLOCK_THREADS;
        const int tt  = u / 384;
        const int rem = u - tt * 384;
        const int row = rem / 48;
        const int z4  = rem - row * 48;
        const int grow = min(max(Y0 - 1 + row, 0), NY - 1);
        sbv[k] = (tt ? pred : label) + bbase + grow * NZ + z4 * 4;
        lov[k] = (tt * ROWS + row) * NZ + z4 * 4;
    }

    float wy[3];
    #pragma unroll
    for (int r = 0; r < 3; ++r) {
        const int yy = y + r - 1;
        wy[r] = ((unsigned)yy < (unsigned)NY) ? 1.f : 0.f;
    }
    // z-boundary / lane-seam masks
    const float wm = (tx == 0)      ? 0.f : 1.f;
    const float we = (tx == TZ - 1) ? 0.f : 1.f;

    const bool safe = (blockIdx.x >= 1) && (blockIdx.x <= NYT - 2) &&
                      (blockIdx.y >= 1) && (blockIdx.y <= NXB - 2);

    const float acc = safe
        ? march<true >(sbv[0], sbv[1], sbv[2], sbv[3],
                       lov[0], lov[1], lov[2], lov[3], tile,
                       ty, tx, wy, wm, we, xs0)
        : march<false>(sbv[0], sbv[1], sbv[2], sbv[3],
                       lov[0], lov[1], lov[2], lov[3], tile,
                       ty, tx, wy, wm, we, xs0);

    // wave (64) reduction, then block sum
    float a = acc;
    #pragma unroll
    for (int o = 32; o > 0; o >>= 1)
        a += __shfl_down(a, o, 64);

    __shared__ float wsum[BLOCK_THREADS / 64];
    if ((tid & 63) == 0) wsum[tid >> 6] = a;
    __syncthreads();
    if (tid == 0) {
        float s = 0.f;
        #pragma unroll
        for (int w = 0; w < BLOCK_THREADS / 64; ++w) s += wsum[w];
        partials[blockIdx.x + (int)gridDim.x * (blockIdx.y + (int)gridDim.y * blockIdx.z)] = s;
    }
}

__global__ __launch_bounds__(256)
void ncc_reduce(const float* __restrict__ partials, int n, float* __restrict__ out)
{
    __shared__ double sh[256];
    double s = 0.0;
    for (int i = threadIdx.x; i < n; i += 256) s += (double)partials[i];
    sh[threadIdx.x] = s;
    __syncthreads();
    for (int off = 128; off > 0; off >>= 1) {
        if ((int)threadIdx.x < off) sh[threadIdx.x] += sh[threadIdx.x + off];
        __syncthreads();
    }
    if (threadIdx.x == 0) {
        const double nvox = (double)NB * NX * NY * NZ;
        out[0] = (float)(-sh[0] / nvox);
    }
}

extern "C" void kernel_launch(void* const* d_in, const int* in_sizes, int n_in,
                              void* d_out, int out_size, void* d_ws, size_t ws_size,
                              hipStream_t stream) {
    const float* pred  = (const float*)d_in[0];
    const float* label = (const float*)d_in[1];
    float* out = (float*)d_out;
    float* partials = (float*)d_ws;

    dim3 block(TZ, BY, 1);                 // 32 x 6 = 192 threads
    dim3 grid(NYT, NXB, NB);               // 32 x 48 x 2 = 3072 blocks

    ncc_partial<<<grid, block, 0, stream>>>(pred, label, partials);
    ncc_reduce<<<1, 256, 0, stream>>>(partials, NBLK, out);
}